// Round 5
// baseline (25.137 us; speedup 1.0000x reference)
//
#include <hip/hip_runtime.h>
#include <stdint.h>

#define BATCH 512
#define D_IN 1024
#define D_OUT 1024
#define BITSZ 128
#define N_STEPS (D_IN - 2)  // 1022

// Table covers idx in [IBASE, 1024). P(any idx < IBASE) ~ 65536 * 2^-64 ~ 4e-15;
// a direct-cipher fallback in k_acc keeps exactness for the impossible case.
#define IBASE 960
#define ICAP 64  // table rows per t column

// ws layout (nothing needs zeroing)
#define WS_V_OFF 0u
#define WS_V_BYTES (BATCH * BITSZ * 4u)            // 262144
#define WS_TAB_OFF (WS_V_OFF + WS_V_BYTES)         // 262144
#define WS_TAB_BYTES (BITSZ * ICAP * 32u * 4u)     // 1048576
#define WS_NEEDED (WS_TAB_OFF + WS_TAB_BYTES)      // 1310720

// k_acc transposed staging: 32 d-word columns, padded stride (132*4B = 528B:
// 16B-aligned columns, bank(jj,wrd) = (4*wrd+jj)%32 -> spread on writes).
#define TSTRIDE 132

__host__ __device__ __forceinline__ uint32_t rotl32(uint32_t x, uint32_t d) {
  return (x << d) | (x >> (32u - d));
}

// Threefry-2x32, 20 rounds, exactly as jax/_src/prng.py lowering.
__host__ __device__ __forceinline__ void threefry2x32(uint32_t k0, uint32_t k1,
                                                      uint32_t& x0, uint32_t& x1) {
  const uint32_t k2 = k0 ^ k1 ^ 0x1BD11BDAu;
  x0 += k0; x1 += k1;
#define TFR(r) { x0 += x1; x1 = rotl32(x1, (r)); x1 ^= x0; }
  TFR(13) TFR(15) TFR(26) TFR(6)
  x0 += k1; x1 += k2 + 1u;
  TFR(17) TFR(29) TFR(16) TFR(24)
  x0 += k2; x1 += k0 + 2u;
  TFR(13) TFR(15) TFR(26) TFR(6)
  x0 += k0; x1 += k1 + 3u;
  TFR(17) TFR(29) TFR(16) TFR(24)
  x0 += k1; x1 += k2 + 4u;
  TFR(13) TFR(15) TFR(26) TFR(6)
  x0 += k2; x1 += k0 + 5u;
#undef TFR
}

// jax_threefry_partitionable random_bits -> uniform [0,1):
// counts=(0,n), 20-round threefry, 32-bit fold, mantissa trick.
__device__ __forceinline__ float runif(uint32_t k0, uint32_t k1, uint32_t n) {
  uint32_t x0 = 0u, x1 = n;
  threefry2x32(k0, k1, x0, x1);
  const uint32_t b = x0 ^ x1;
  return __uint_as_float((b >> 9) | 0x3f800000u) - 1.0f;
}

// idx = max row s+1 whose coin is False, scanned top-down in speculative
// ILP-4 batches (4 independent ciphers hide the dependent threefry chain).
__device__ __forceinline__ int scan_idx(int b, int t,
                                        uint32_t ck0, uint32_t ck1) {
  const uint32_t bt = ((uint32_t)b << 7) + (uint32_t)t;
  int idx = 0;
  int s;
  for (s = N_STEPS - 1; s >= 3; s -= 4) {
    // coins linear index: s*(BATCH*BITSZ) + b*BITSZ + t
    const float u0 = runif(ck0, ck1, ((uint32_t)(s)     << 16) + bt);
    const float u1 = runif(ck0, ck1, ((uint32_t)(s - 1) << 16) + bt);
    const float u2 = runif(ck0, ck1, ((uint32_t)(s - 2) << 16) + bt);
    const float u3 = runif(ck0, ck1, ((uint32_t)(s - 3) << 16) + bt);
    if (u0 > 0.5f) { idx = s + 1; break; }
    if (u1 > 0.5f) { idx = s;     break; }
    if (u2 > 0.5f) { idx = s - 1; break; }
    if (u3 > 0.5f) { idx = s - 2; break; }
  }
  if (idx == 0 && s < 3) {  // tail: s = 1 and s = 0
    const float u0 = runif(ck0, ck1, (1u << 16) + bt);
    const float u1 = runif(ck0, ck1, bt);
    if (u0 > 0.5f)      idx = 2;
    else if (u1 > 0.5f) idx = 1;
  }
  return idx;
}

// Kernel A: block = (t, d-quarter q). Each block recomputes all 512 scans for
// its t (local, no cross-block dependency), builds the LDS presence bitmap,
// and generates each present row's 256-bit d-quarter (1 cipher per (row,d),
// ballot-packed). The q==0 block also writes v[b*128+t] = xbit ? idx : -1.
__global__ void __launch_bounds__(256) k_tabx(const float* __restrict__ x,
                                              const float* __restrict__ w,
                                              int* __restrict__ v,
                                              uint32_t* __restrict__ tab,
                                              uint32_t ck0, uint32_t ck1,
                                              uint32_t xk0, uint32_t xk1,
                                              uint32_t wk0, uint32_t wk1) {
  const int t = blockIdx.x & 127;
  const int q = blockIdx.x >> 7;
  const int tid = threadIdx.x;

  __shared__ uint32_t s_bm[2];
  if (tid < 2) s_bm[tid] = 0u;
  __syncthreads();

#pragma unroll
  for (int h = 0; h < 2; ++h) {
    const int b = tid + h * 256;
    const int idx = scan_idx(b, t, ck0, ck1);
    // x_bits linear index: b*(D_IN*BITSZ) + idx*BITSZ + t
    const float ux = runif(xk0, xk1,
        ((uint32_t)b << 17) + ((uint32_t)idx << 7) + (uint32_t)t);
    const int xb = (ux <= x[b * D_IN + idx]) ? 1 : 0;
    if (q == 0) v[b * BITSZ + t] = xb ? idx : -1;
    if (xb && idx >= IBASE) {
      const int bp = idx - IBASE;
      atomicOr(&s_bm[bp >> 5], 1u << (bp & 31));
    }
  }
  __syncthreads();

  unsigned long long bm = (unsigned long long)s_bm[0] |
                          ((unsigned long long)s_bm[1] << 32);
  const int d = q * 256 + tid;
  const int lane = tid & 63;
  const int wbase = (d >> 5) & ~1;  // q*8 + wave*2 (even)
  const float* wcol = w + d;
  while (bm) {
    const int j = __builtin_ctzll(bm);
    bm &= bm - 1ull;
    const int i = IBASE + j;
    // w_bits linear index: i*(D_OUT*BITSZ) + d*BITSZ + t
    const float u = runif(wk0, wk1,
        ((uint32_t)i << 17) + ((uint32_t)d << 7) + (uint32_t)t);
    const unsigned long long mb = __ballot(u <= wcol[i * D_OUT]);
    uint32_t* row = tab + (((t << 6) + j) << 5);
    if (lane == 0)  row[wbase]     = (uint32_t)mb;
    if (lane == 32) row[wbase + 1] = (uint32_t)(mb >> 32);
  }
}

// Standalone scan kernel — only used on the tiny-ws fallback path.
__global__ void __launch_bounds__(256) k_idx(const float* __restrict__ x,
                                             int* __restrict__ v,
                                             uint32_t ck0, uint32_t ck1,
                                             uint32_t xk0, uint32_t xk1) {
  const int tid = blockIdx.x * 256 + threadIdx.x;  // 0..65535
  const int b = tid >> 7;
  const int t = tid & 127;
  const int idx = scan_idx(b, t, ck0, ck1);
  const float ux = runif(xk0, xk1,
      ((uint32_t)b << 17) + ((uint32_t)idx << 7) + (uint32_t)t);
  const int xb = (ux <= x[b * D_IN + idx]) ? 1 : 0;
  v[tid] = xb ? idx : -1;
}

// Kernel B: block per b. Compact active (t,idx), stage rows TRANSPOSED into
// LDS ([32 dw][TSTRIDE]), accumulate with ds_read_b128 (4 rows per read,
// broadcast within half-wave).
__global__ void __launch_bounds__(1024) k_acc(const float* __restrict__ w,
                                              const int* __restrict__ v,
                                              const uint32_t* __restrict__ tab,
                                              float* __restrict__ out,
                                              uint32_t wk0, uint32_t wk1,
                                              int use_tab) {
  const int b = blockIdx.x;
  const int tid = threadIdx.x;  // == d

  __shared__ __align__(16) uint32_t s_tab2[32 * TSTRIDE];  // 16.9 KB
  __shared__ int s_list[BITSZ];
  __shared__ int s_wcnt[2];
  __shared__ int s_anyfb;

  if (tid == 0) s_anyfb = use_tab ? 0 : 1;

  unsigned long long mb = 0;
  int code = -1;
  bool act = false;
  if (tid < BITSZ) {
    code = v[b * BITSZ + tid];
    act = code >= 0;
    mb = __ballot(act);
    if ((tid & 63) == 0) s_wcnt[tid >> 6] = __popcll(mb);
  }
  __syncthreads();  // s_anyfb + s_wcnt visible
  const int m = s_wcnt[0] + s_wcnt[1];
  const int m4 = (m + 3) & ~3;
  if (tid < BITSZ && act) {
    const int lane = tid & 63;
    const int pos = ((tid >= 64) ? s_wcnt[0] : 0) +
                    __popcll(mb & ((1ull << lane) - 1ull));
    s_list[pos] = (code << 7) | tid;  // idx<<7 | t
    if (code < IBASE) atomicOr(&s_anyfb, 1);
  }
  __syncthreads();

  if (s_anyfb == 0) {
    // Transposed staging: column = d-word (wrd), row index jj along stride.
    const int wrd = tid & 31;
    for (int jj = tid >> 5; jj < m; jj += 32) {
      const int e = s_list[jj];
      const int i = e >> 7, t = e & 127;
      s_tab2[wrd * TSTRIDE + jj] = tab[(((t << 6) + (i - IBASE)) << 5) + wrd];
    }
    if (tid < 32)
      for (int jj = m; jj < m4; ++jj) s_tab2[tid * TSTRIDE + jj] = 0u;
    __syncthreads();

    const int dw = tid >> 5, db = tid & 31;
    const uint32_t* colp = &s_tab2[dw * TSTRIDE];
    int acc = 0;
    for (int k = 0; k < m4; k += 4) {
      const uint4 r = *(const uint4*)(colp + k);  // ds_read_b128
      acc += (r.x >> db) & 1u;
      acc += (r.y >> db) & 1u;
      acc += (r.z >> db) & 1u;
      acc += (r.w >> db) & 1u;
    }
    out[b * D_OUT + tid] = (float)acc * (1.0f / (float)BITSZ);
  } else {
    // Correctness fallback (idx < IBASE or tiny ws): direct ciphers.
    int acc = 0;
    for (int jj = 0; jj < m; ++jj) {
      const int e = s_list[jj];
      const int i = e >> 7, t = e & 127;
      const float u = runif(wk0, wk1,
          ((uint32_t)i << 17) + ((uint32_t)tid << 7) + (uint32_t)t);
      acc += (u <= w[i * D_OUT + tid]) ? 1 : 0;
    }
    out[b * D_OUT + tid] = (float)acc * (1.0f / (float)BITSZ);
  }
}

struct TFKeys { uint32_t xk0, xk1, wk0, wk1, ck0, ck1; };

static TFKeys derive_keys() {
  TFKeys K;
  // partitionable split: key_i = both output words of E_{(0,42)}(0, i)
  uint32_t a0 = 0, a1 = 0; threefry2x32(0u, 42u, a0, a1); K.xk0 = a0; K.xk1 = a1;
  uint32_t b0 = 0, b1 = 1; threefry2x32(0u, 42u, b0, b1); K.wk0 = b0; K.wk1 = b1;
  uint32_t c0 = 0, c1 = 2; threefry2x32(0u, 42u, c0, c1); K.ck0 = c0; K.ck1 = c1;
  return K;
}

extern "C" void kernel_launch(void* const* d_in, const int* in_sizes, int n_in,
                              void* d_out, int out_size, void* d_ws, size_t ws_size,
                              hipStream_t stream) {
  const float* x = (const float*)d_in[0];
  const float* w = (const float*)d_in[1];
  if (n_in >= 2 && in_sizes[0] == D_IN * D_OUT && in_sizes[1] == BATCH * D_IN) {
    const float* tmp = x; x = w; w = tmp;
  }
  float* out = (float*)d_out;
  char* ws = (char*)d_ws;
  int* v = (int*)(ws + WS_V_OFF);
  uint32_t* tab = (uint32_t*)(ws + WS_TAB_OFF);

  const int use_tab = (ws_size >= WS_NEEDED) ? 1 : 0;
  const TFKeys K = derive_keys();

  if (use_tab) {
    hipLaunchKernelGGL(k_tabx, dim3(BITSZ * 4), dim3(256), 0, stream,
                       x, w, v, tab, K.ck0, K.ck1, K.xk0, K.xk1, K.wk0, K.wk1);
  } else {
    hipLaunchKernelGGL(k_idx, dim3((BATCH * BITSZ) / 256), dim3(256), 0, stream,
                       x, v, K.ck0, K.ck1, K.xk0, K.xk1);
  }
  hipLaunchKernelGGL(k_acc, dim3(BATCH), dim3(D_OUT), 0, stream,
                     w, v, tab, out, K.wk0, K.wk1, use_tab);
}

// Round 6
// 22.389 us; speedup vs baseline: 1.1228x; 1.1228x over previous
//
#include <hip/hip_runtime.h>
#include <stdint.h>

#define BATCH 512
#define D_IN 1024
#define D_OUT 1024
#define BITSZ 128
#define N_STEPS (D_IN - 2)  // 1022

// Table covers idx in [IBASE, 1024). P(any idx < IBASE) ~ 65536 * 2^-64 ~ 4e-15;
// a direct-cipher fallback in k_acc keeps exactness for the impossible case.
#define IBASE 960
#define ICAP 64  // table rows per t column

// ws layout (nothing needs zeroing)
#define WS_V_OFF 0u
#define WS_V_BYTES (BATCH * BITSZ * 4u)            // 262144   v[b*128+t]
#define WS_VT_OFF (WS_V_OFF + WS_V_BYTES)
#define WS_VT_BYTES (BITSZ * BATCH * 4u)           // 262144   vT[t*512+b]
#define WS_TAB_OFF (WS_VT_OFF + WS_VT_BYTES)
#define WS_TAB_BYTES (BITSZ * ICAP * 32u * 4u)     // 1048576
#define WS_NEEDED (WS_TAB_OFF + WS_TAB_BYTES)

// k_acc transposed staging: 32 d-word columns, padded stride (132*4B = 528B:
// 16B-aligned columns, bank(jj,wrd) = (4*wrd+jj)%32 -> spread on writes).
#define TSTRIDE 132

__host__ __device__ __forceinline__ uint32_t rotl32(uint32_t x, uint32_t d) {
  return (x << d) | (x >> (32u - d));
}

// Threefry-2x32, 20 rounds, exactly as jax/_src/prng.py lowering.
__host__ __device__ __forceinline__ void threefry2x32(uint32_t k0, uint32_t k1,
                                                      uint32_t& x0, uint32_t& x1) {
  const uint32_t k2 = k0 ^ k1 ^ 0x1BD11BDAu;
  x0 += k0; x1 += k1;
#define TFR(r) { x0 += x1; x1 = rotl32(x1, (r)); x1 ^= x0; }
  TFR(13) TFR(15) TFR(26) TFR(6)
  x0 += k1; x1 += k2 + 1u;
  TFR(17) TFR(29) TFR(16) TFR(24)
  x0 += k2; x1 += k0 + 2u;
  TFR(13) TFR(15) TFR(26) TFR(6)
  x0 += k0; x1 += k1 + 3u;
  TFR(17) TFR(29) TFR(16) TFR(24)
  x0 += k1; x1 += k2 + 4u;
  TFR(13) TFR(15) TFR(26) TFR(6)
  x0 += k2; x1 += k0 + 5u;
#undef TFR
}

// jax_threefry_partitionable random_bits -> uniform [0,1):
// counts=(0,n), 20-round threefry, 32-bit fold, mantissa trick.
__device__ __forceinline__ float runif(uint32_t k0, uint32_t k1, uint32_t n) {
  uint32_t x0 = 0u, x1 = n;
  threefry2x32(k0, k1, x0, x1);
  const uint32_t b = x0 ^ x1;
  return __uint_as_float((b >> 9) | 0x3f800000u) - 1.0f;
}

// idx = max row s+1 whose coin is False, scanned top-down in speculative
// ILP-4 batches (4 independent ciphers hide the dependent threefry chain).
__device__ __forceinline__ int scan_idx(uint32_t bt, uint32_t ck0, uint32_t ck1) {
  int idx = 0;
  int s;
  for (s = N_STEPS - 1; s >= 3; s -= 4) {
    // coins linear index: s*(BATCH*BITSZ) + b*BITSZ + t
    const float u0 = runif(ck0, ck1, ((uint32_t)(s)     << 16) + bt);
    const float u1 = runif(ck0, ck1, ((uint32_t)(s - 1) << 16) + bt);
    const float u2 = runif(ck0, ck1, ((uint32_t)(s - 2) << 16) + bt);
    const float u3 = runif(ck0, ck1, ((uint32_t)(s - 3) << 16) + bt);
    if (u0 > 0.5f) { idx = s + 1; break; }
    if (u1 > 0.5f) { idx = s;     break; }
    if (u2 > 0.5f) { idx = s - 1; break; }
    if (u3 > 0.5f) { idx = s - 2; break; }
  }
  if (idx == 0 && s < 3) {  // tail: s = 1 and s = 0
    const float u0 = runif(ck0, ck1, (1u << 16) + bt);
    const float u1 = runif(ck0, ck1, bt);
    if (u0 > 0.5f)      idx = 2;
    else if (u1 > 0.5f) idx = 1;
  }
  return idx;
}

// Kernel 1: thread per (b,t). Writes v[b*128+t] (coalesced, for k_acc) and
// vT[t*512+b] (for k_tab's coalesced per-b read).
__global__ void __launch_bounds__(256) k_idx(const float* __restrict__ x,
                                             int* __restrict__ v,
                                             int* __restrict__ vt,
                                             uint32_t ck0, uint32_t ck1,
                                             uint32_t xk0, uint32_t xk1,
                                             int use_tab) {
  const int tid = blockIdx.x * 256 + threadIdx.x;  // 0..65535
  const int b = tid >> 7;
  const int t = tid & 127;
  const int idx = scan_idx((uint32_t)tid, ck0, ck1);
  // x_bits linear index: b*(D_IN*BITSZ) + idx*BITSZ + t
  const float ux = runif(xk0, xk1,
      ((uint32_t)b << 17) + ((uint32_t)idx << 7) + (uint32_t)t);
  const int xb = (ux <= x[b * D_IN + idx]) ? 1 : 0;
  const int val = xb ? idx : -1;
  v[tid] = val;
  if (use_tab) vt[t * BATCH + b] = val;
}

// Kernel 2: block = (t, d-half h). 256 blocks x 1024 threads (1 block/CU).
// Build per-t presence from vT (coalesced), compact row list, then generate
// table bits with TWO rows in flight (thread-groups A/B take even/odd rows),
// one cipher per (row, d), ballot-packed into the global table.
__global__ void __launch_bounds__(1024) k_tab(const float* __restrict__ w,
                                              const int* __restrict__ vt,
                                              uint32_t* __restrict__ tab,
                                              uint32_t wk0, uint32_t wk1) {
  const int t = blockIdx.x >> 1;
  const int h = blockIdx.x & 1;
  const int tid = threadIdx.x;

  __shared__ uint32_t s_bm[2];
  __shared__ int s_rows[ICAP];
  if (tid < 2) s_bm[tid] = 0u;
  __syncthreads();

  unsigned long long m64 = 0;
  if (tid < BATCH) {
    const int code = vt[t * BATCH + tid];  // b = tid, coalesced
    if (code >= IBASE) m64 = 1ull << (code - IBASE);
  }
  for (int off = 32; off; off >>= 1) m64 |= __shfl_down(m64, off);
  if ((tid & 63) == 0 && tid < BATCH) {
    if ((uint32_t)m64)         atomicOr(&s_bm[0], (uint32_t)m64);
    if ((uint32_t)(m64 >> 32)) atomicOr(&s_bm[1], (uint32_t)(m64 >> 32));
  }
  __syncthreads();

  const unsigned long long bm = (unsigned long long)s_bm[0] |
                                ((unsigned long long)s_bm[1] << 32);
  const int cnt = __popcll(bm);
  if (tid < 64 && ((bm >> tid) & 1ull))
    s_rows[__popcll(bm & ((1ull << tid) - 1ull))] = tid;
  __syncthreads();

  const int g = (tid < 512) ? 0 : 1;        // row-parity group
  const int dl = (tid < 512) ? tid : (tid - 512);
  const int d = h * 512 + dl;
  const int lane = tid & 63;
  const int wbase = (d >> 5) & ~1;          // even word pair for this wave
  const float* wcol = w + d;
  for (int r = g; r < cnt; r += 2) {
    const int j = s_rows[r];
    const int i = IBASE + j;
    // w_bits linear index: i*(D_OUT*BITSZ) + d*BITSZ + t
    const float u = runif(wk0, wk1,
        ((uint32_t)i << 17) + ((uint32_t)d << 7) + (uint32_t)t);
    const unsigned long long mb = __ballot(u <= wcol[i * D_OUT]);
    uint32_t* row = tab + (((t << 6) + j) << 5);
    if (lane == 0)  row[wbase]     = (uint32_t)mb;
    if (lane == 32) row[wbase + 1] = (uint32_t)(mb >> 32);
  }
}

// Kernel 3: block per b, 512 threads (4 blocks/CU -> full 32 waves/CU).
// Thread handles d = tid and d = tid+512. Compact active (t,idx), stage rows
// TRANSPOSED into LDS ([32 dw][TSTRIDE]), accumulate via ds_read_b128.
__global__ void __launch_bounds__(512) k_acc(const float* __restrict__ w,
                                             const int* __restrict__ v,
                                             const uint32_t* __restrict__ tab,
                                             float* __restrict__ out,
                                             uint32_t wk0, uint32_t wk1,
                                             int use_tab) {
  const int b = blockIdx.x;
  const int tid = threadIdx.x;

  __shared__ __align__(16) uint32_t s_tab2[32 * TSTRIDE];  // 16.9 KB
  __shared__ int s_list[BITSZ];
  __shared__ int s_wcnt[2];
  __shared__ int s_anyfb;

  if (tid == 0) s_anyfb = use_tab ? 0 : 1;

  unsigned long long mb = 0;
  int code = -1;
  bool act = false;
  if (tid < BITSZ) {
    code = v[b * BITSZ + tid];
    act = code >= 0;
    mb = __ballot(act);
    if ((tid & 63) == 0) s_wcnt[tid >> 6] = __popcll(mb);
  }
  __syncthreads();  // s_anyfb + s_wcnt visible
  const int m = s_wcnt[0] + s_wcnt[1];
  const int m4 = (m + 3) & ~3;
  if (tid < BITSZ && act) {
    const int lane = tid & 63;
    const int pos = ((tid >= 64) ? s_wcnt[0] : 0) +
                    __popcll(mb & ((1ull << lane) - 1ull));
    s_list[pos] = (code << 7) | tid;  // idx<<7 | t
    if (code < IBASE) atomicOr(&s_anyfb, 1);
  }
  __syncthreads();

  if (s_anyfb == 0) {
    // Transposed staging: column = d-word (wrd), row index jj along stride.
    const int wrd = tid & 31;
    for (int jj = tid >> 5; jj < m; jj += 16) {
      const int e = s_list[jj];
      const int i = e >> 7, t = e & 127;
      s_tab2[wrd * TSTRIDE + jj] = tab[(((t << 6) + (i - IBASE)) << 5) + wrd];
    }
    if (tid < 32)
      for (int jj = m; jj < m4; ++jj) s_tab2[tid * TSTRIDE + jj] = 0u;
    __syncthreads();

    const int dw0 = tid >> 5, db = tid & 31;  // dw0 in 0..15
    const int dw1 = dw0 + 16;
    const uint32_t* c0 = &s_tab2[dw0 * TSTRIDE];
    const uint32_t* c1 = &s_tab2[dw1 * TSTRIDE];
    int a0 = 0, a1 = 0;
    for (int k = 0; k < m4; k += 4) {
      const uint4 r0 = *(const uint4*)(c0 + k);  // ds_read_b128
      const uint4 r1 = *(const uint4*)(c1 + k);
      a0 += (r0.x >> db) & 1u; a0 += (r0.y >> db) & 1u;
      a0 += (r0.z >> db) & 1u; a0 += (r0.w >> db) & 1u;
      a1 += (r1.x >> db) & 1u; a1 += (r1.y >> db) & 1u;
      a1 += (r1.z >> db) & 1u; a1 += (r1.w >> db) & 1u;
    }
    out[b * D_OUT + tid]       = (float)a0 * (1.0f / (float)BITSZ);
    out[b * D_OUT + tid + 512] = (float)a1 * (1.0f / (float)BITSZ);
  } else {
    // Correctness fallback (idx < IBASE or tiny ws): direct ciphers, 2 d's.
    const int d0 = tid, d1 = tid + 512;
    int a0 = 0, a1 = 0;
    for (int jj = 0; jj < m; ++jj) {
      const int e = s_list[jj];
      const int i = e >> 7, t = e & 127;
      const float u0 = runif(wk0, wk1,
          ((uint32_t)i << 17) + ((uint32_t)d0 << 7) + (uint32_t)t);
      const float u1 = runif(wk0, wk1,
          ((uint32_t)i << 17) + ((uint32_t)d1 << 7) + (uint32_t)t);
      a0 += (u0 <= w[i * D_OUT + d0]) ? 1 : 0;
      a1 += (u1 <= w[i * D_OUT + d1]) ? 1 : 0;
    }
    out[b * D_OUT + d0] = (float)a0 * (1.0f / (float)BITSZ);
    out[b * D_OUT + d1] = (float)a1 * (1.0f / (float)BITSZ);
  }
}

struct TFKeys { uint32_t xk0, xk1, wk0, wk1, ck0, ck1; };

static TFKeys derive_keys() {
  TFKeys K;
  // partitionable split: key_i = both output words of E_{(0,42)}(0, i)
  uint32_t a0 = 0, a1 = 0; threefry2x32(0u, 42u, a0, a1); K.xk0 = a0; K.xk1 = a1;
  uint32_t b0 = 0, b1 = 1; threefry2x32(0u, 42u, b0, b1); K.wk0 = b0; K.wk1 = b1;
  uint32_t c0 = 0, c1 = 2; threefry2x32(0u, 42u, c0, c1); K.ck0 = c0; K.ck1 = c1;
  return K;
}

extern "C" void kernel_launch(void* const* d_in, const int* in_sizes, int n_in,
                              void* d_out, int out_size, void* d_ws, size_t ws_size,
                              hipStream_t stream) {
  const float* x = (const float*)d_in[0];
  const float* w = (const float*)d_in[1];
  if (n_in >= 2 && in_sizes[0] == D_IN * D_OUT && in_sizes[1] == BATCH * D_IN) {
    const float* tmp = x; x = w; w = tmp;
  }
  float* out = (float*)d_out;
  char* ws = (char*)d_ws;
  int* v = (int*)(ws + WS_V_OFF);
  int* vt = (int*)(ws + WS_VT_OFF);
  uint32_t* tab = (uint32_t*)(ws + WS_TAB_OFF);

  const int use_tab = (ws_size >= WS_NEEDED) ? 1 : 0;
  const TFKeys K = derive_keys();

  hipLaunchKernelGGL(k_idx, dim3((BATCH * BITSZ) / 256), dim3(256), 0, stream,
                     x, v, vt, K.ck0, K.ck1, K.xk0, K.xk1, use_tab);
  if (use_tab)
    hipLaunchKernelGGL(k_tab, dim3(BITSZ * 2), dim3(1024), 0, stream,
                       w, vt, tab, K.wk0, K.wk1);
  hipLaunchKernelGGL(k_acc, dim3(BATCH), dim3(512), 0, stream,
                     w, v, tab, out, K.wk0, K.wk1, use_tab);
}